// Round 2
// baseline (418.009 us; speedup 1.0000x reference)
//
#include <hip/hip_runtime.h>
#include <math.h>

// DTW loss: B=128, L1=L2=512, D=16.
// One WAVE (64 threads) per batch; thread t owns columns 8t..8t+7.
// Per-row (min,+) pair scan: local 8-wide in-register scan, then 6-step
// wave shfl scan, no LDS, no __syncthreads. Distances via dot-form with
// y in registers and v_pk_fma_f32; computed one row ahead to overlap the
// shfl dependency chain.

#define TL1 512
#define TL2 512
#define TD  16
#define TNB 128
#define BIGF 3.0e38f

typedef float f32x2 __attribute__((ext_vector_type(2)));

__device__ inline f32x2 pk_fma(f32x2 a, f32x2 b, f32x2 c) {
    f32x2 d;
    asm("v_pk_fma_f32 %0, %1, %2, %3" : "=v"(d) : "v"(a), "v"(b), "v"(c));
    return d;
}

__global__ __launch_bounds__(64, 1) void dtw_dp_kernel(const float* __restrict__ s1,
                                                       const float* __restrict__ s2,
                                                       float* __restrict__ ws) {
    const int b = blockIdx.x;
    const int t = threadIdx.x;   // 0..63, == lane

    // y: 8 columns x 16 dims -> 64 f32x2 registers; ysq per column
    const float* s2b = s2 + ((size_t)b * TL2 + 8 * (size_t)t) * TD;
    f32x2 y2[8][8];
    float ysq[8];
    #pragma unroll
    for (int k = 0; k < 8; ++k) {
        #pragma unroll
        for (int p = 0; p < 8; ++p)
            y2[k][p] = *reinterpret_cast<const f32x2*>(s2b + k * TD + 2 * p);
        f32x2 acc = {0.f, 0.f};
        #pragma unroll
        for (int p = 0; p < 8; ++p) acc = pk_fma(y2[k][p], y2[k][p], acc);
        ysq[k] = acc.x + acc.y;
    }

    const float* s1b = s1 + (size_t)b * TL1 * TD;

    // cost of row i into c[8]
    auto compute_costs = [&](int i, float* c) {
        const float* xr = s1b + i * TD;
        f32x2 x2[8];
        #pragma unroll
        for (int p = 0; p < 8; ++p)
            x2[p] = *reinterpret_cast<const f32x2*>(xr + 2 * p);
        f32x2 xs = {0.f, 0.f};
        #pragma unroll
        for (int p = 0; p < 8; ++p) xs = pk_fma(x2[p], x2[p], xs);
        float xsq = xs.x + xs.y;
        #pragma unroll
        for (int k = 0; k < 8; ++k) {
            f32x2 acc = {0.f, 0.f};
            #pragma unroll
            for (int p = 0; p < 8; ++p) acc = pk_fma(x2[p], y2[k][p], acc);
            c[k] = fmaf(-2.f, acc.x + acc.y, xsq + ysq[k]);
        }
    };

    float cc[8];
    compute_costs(0, cc);

    float prev[8];

    for (int i = 0; i < TL1; ++i) {
        // prefetch+compute next row's costs (independent of the scan chain)
        float cn[8];
        if (i + 1 < TL1) compute_costs(i + 1, cn);

        // a_k = c_k + m_k
        float a[8];
        if (i == 0) {
            #pragma unroll
            for (int k = 0; k < 8; ++k)
                a[k] = cc[k] + ((t == 0 && k == 0) ? 0.f : BIGF);
        } else {
            float pe = __shfl_up(prev[7], 1);   // DTW(i-1, 8t-1)
            float m0 = (t == 0) ? prev[0] : fminf(prev[0], pe);
            a[0] = cc[0] + m0;
            #pragma unroll
            for (int k = 1; k < 8; ++k)
                a[k] = cc[k] + fminf(prev[k], prev[k - 1]);
        }

        // local inclusive pair scan over the 8 columns
        float Cl[8], Al[8];
        float C = cc[0], A = a[0];
        Cl[0] = C; Al[0] = A;
        #pragma unroll
        for (int k = 1; k < 8; ++k) {
            A = fminf(A + cc[k], a[k]);
            C = C + cc[k];
            Cl[k] = C; Al[k] = A;
        }

        // 6-step wave inclusive pair scan on thread aggregates
        #pragma unroll
        for (int d = 1; d < 64; d <<= 1) {
            float Cu = __shfl_up(C, d);
            float Au = __shfl_up(A, d);
            if (t >= d) {
                A = fminf(Au + C, A);   // uses pre-update C
                C = Cu + C;
            }
        }

        // exclusive prefix (threads 0..t-1); identity A-part = BIG
        float Apre = __shfl_up(A, 1);
        if (t == 0) Apre = BIGF;

        #pragma unroll
        for (int k = 0; k < 8; ++k)
            prev[k] = fminf(Apre + Cl[k], Al[k]);

        #pragma unroll
        for (int k = 0; k < 8; ++k) cc[k] = cn[k];
    }

    if (t == 63) ws[b] = sqrtf(prev[7]);
}

__global__ void dtw_reduce_kernel(const float* __restrict__ ws, float* __restrict__ out) {
    const int t = threadIdx.x;          // 64 threads
    float v = ws[t] + ws[t + 64];
    #pragma unroll
    for (int d2 = 32; d2 > 0; d2 >>= 1) v += __shfl_down(v, d2);
    if (t == 0) out[0] = v * (1.0f / TNB);
}

extern "C" void kernel_launch(void* const* d_in, const int* in_sizes, int n_in,
                              void* d_out, int out_size, void* d_ws, size_t ws_size,
                              hipStream_t stream) {
    const float* s1 = (const float*)d_in[0];
    const float* s2 = (const float*)d_in[1];
    float* ws  = (float*)d_ws;
    float* out = (float*)d_out;

    dtw_dp_kernel<<<TNB, 64, 0, stream>>>(s1, s2, ws);
    dtw_reduce_kernel<<<1, 64, 0, stream>>>(ws, out);
}

// Round 3
// 223.844 us; speedup vs baseline: 1.8674x; 1.8674x over previous
//
#include <hip/hip_runtime.h>
#include <math.h>

// DTW loss: B=128, L1=L2=512, D=16.
// One wave per batch, 8 cols/lane. Per-row (min,+) pair scan done entirely
// with DPP (VALU-latency cross-lane) instead of ds_bpermute shfls:
//   4x row_shr (1,2,4,8) + row_bcast15 (rows 1,3) + row_bcast31 (rows 2,3),
// identity (C=0, A=BIG) injected via update_dpp's `old` operand.
// Exclusive prefix + row-boundary exchange via wave_shr:1 DPP.

#define TL1 512
#define TL2 512
#define TD  16
#define TNB 128
#define BIGF 3.0e38f

typedef float f32x2 __attribute__((ext_vector_type(2)));

__device__ inline f32x2 pk_fma(f32x2 a, f32x2 b, f32x2 c) {
    f32x2 d;
    asm("v_pk_fma_f32 %0, %1, %2, %3" : "=v"(d) : "v"(a), "v"(b), "v"(c));
    return d;
}

// DPP move: lanes receiving a valid source get src[srclane]; masked/invalid
// lanes get `old_`.  CTRL: 0x111..0x118 row_shr, 0x142 bcast15, 0x143 bcast31,
// 0x138 wave_shr:1.
template<int CTRL, int RM>
__device__ inline float dppf(float old_, float src) {
    return __int_as_float(__builtin_amdgcn_update_dpp(
        __float_as_int(old_), __float_as_int(src), CTRL, RM, 0xf, false));
}

// one (min,+) pair-scan step: incoming prefix (Ct,At) from DPP, combine
// (must use pre-update C in the A formula)
#define SSTEP(CTRL, RM) { \
    float Ct = dppf<CTRL, RM>(0.0f, C); \
    float At = dppf<CTRL, RM>(BIGF, A); \
    A = fminf(At + C, A); \
    C = Ct + C; \
}

#define ROW_SCAN() { \
    float C = cc[0], A = a[0]; \
    Cl[0] = C; Al[0] = A; \
    _Pragma("unroll") \
    for (int k = 1; k < 8; ++k) { \
        A = fminf(A + cc[k], a[k]); \
        C = C + cc[k]; \
        Cl[k] = C; Al[k] = A; \
    } \
    SSTEP(0x111, 0xf)  /* row_shr:1  */ \
    SSTEP(0x112, 0xf)  /* row_shr:2  */ \
    SSTEP(0x114, 0xf)  /* row_shr:4  */ \
    SSTEP(0x118, 0xf)  /* row_shr:8  */ \
    SSTEP(0x142, 0xa)  /* bcast15 -> rows 1,3 */ \
    SSTEP(0x143, 0xc)  /* bcast31 -> rows 2,3 */ \
    float Apre = dppf<0x138, 0xf>(BIGF, A);  /* exclusive: wave_shr:1 */ \
    _Pragma("unroll") \
    for (int k = 0; k < 8; ++k) prev[k] = fminf(Apre + Cl[k], Al[k]); \
}

__global__ __launch_bounds__(64, 1) void dtw_dp_kernel(const float* __restrict__ s1,
                                                       const float* __restrict__ s2,
                                                       float* __restrict__ ws) {
    const int b = blockIdx.x;
    const int t = threadIdx.x;   // lane 0..63

    // y: 8 columns x 16 dims in registers; ysq per column
    const float* s2b = s2 + ((size_t)b * TL2 + 8 * (size_t)t) * TD;
    f32x2 y2[8][8];
    float ysq[8];
    #pragma unroll
    for (int k = 0; k < 8; ++k) {
        #pragma unroll
        for (int p = 0; p < 8; ++p)
            y2[k][p] = *reinterpret_cast<const f32x2*>(s2b + k * TD + 2 * p);
        f32x2 acc = {0.f, 0.f};
        #pragma unroll
        for (int p = 0; p < 8; ++p) acc = pk_fma(y2[k][p], y2[k][p], acc);
        ysq[k] = acc.x + acc.y;
    }

    const float* s1b = s1 + (size_t)b * TL1 * TD;

    auto costs = [&](int i, float* c) {
        const float* xr = s1b + i * TD;
        f32x2 x2[8];
        #pragma unroll
        for (int p = 0; p < 8; ++p)
            x2[p] = *reinterpret_cast<const f32x2*>(xr + 2 * p);
        f32x2 xs = {0.f, 0.f};
        #pragma unroll
        for (int p = 0; p < 8; ++p) xs = pk_fma(x2[p], x2[p], xs);
        float xsq = xs.x + xs.y;
        #pragma unroll
        for (int k = 0; k < 8; ++k) {
            f32x2 acc = {0.f, 0.f};
            #pragma unroll
            for (int p = 0; p < 8; ++p) acc = pk_fma(x2[p], y2[k][p], acc);
            c[k] = fmaf(-2.f, acc.x + acc.y, xsq + ysq[k]);
        }
    };

    float cc[8], cn[8];
    costs(0, cc);
    costs(1, cn);

    float prev[8];
    float Cl[8], Al[8];

    {   // row 0: only entry is (0,0); m = 0 at col 0, BIG elsewhere
        float a[8];
        #pragma unroll
        for (int k = 0; k < 8; ++k)
            a[k] = cc[k] + ((t == 0 && k == 0) ? 0.f : BIGF);
        ROW_SCAN();
    }

    #pragma unroll 2
    for (int i = 1; i < TL1; ++i) {
        #pragma unroll
        for (int k = 0; k < 8; ++k) cc[k] = cn[k];
        if (i + 1 < TL1) costs(i + 1, cn);

        float a[8];
        float pe = dppf<0x138, 0xf>(BIGF, prev[7]);   // DTW(i-1, 8t-1)
        float m0 = (t == 0) ? prev[0] : fminf(prev[0], pe);
        a[0] = cc[0] + m0;
        #pragma unroll
        for (int k = 1; k < 8; ++k)
            a[k] = cc[k] + fminf(prev[k], prev[k - 1]);

        ROW_SCAN();
    }

    if (t == 63) ws[b] = sqrtf(prev[7]);
}

__global__ void dtw_reduce_kernel(const float* __restrict__ ws, float* __restrict__ out) {
    const int t = threadIdx.x;          // 64 threads
    float v = ws[t] + ws[t + 64];
    #pragma unroll
    for (int d2 = 32; d2 > 0; d2 >>= 1) v += __shfl_down(v, d2);
    if (t == 0) out[0] = v * (1.0f / TNB);
}

extern "C" void kernel_launch(void* const* d_in, const int* in_sizes, int n_in,
                              void* d_out, int out_size, void* d_ws, size_t ws_size,
                              hipStream_t stream) {
    const float* s1 = (const float*)d_in[0];
    const float* s2 = (const float*)d_in[1];
    float* ws  = (float*)d_ws;
    float* out = (float*)d_out;

    dtw_dp_kernel<<<TNB, 64, 0, stream>>>(s1, s2, ws);
    dtw_reduce_kernel<<<1, 64, 0, stream>>>(ws, out);
}

// Round 4
// 199.600 us; speedup vs baseline: 2.0942x; 1.1215x over previous
//
#include <hip/hip_runtime.h>
#include <math.h>

// DTW loss: B=128, L1=L2=512, D=16. One wave per batch, 8 cols/lane.
// DPP (min,+) pair scan per row. R4 changes:
//  - y2 (s2 tile, 128 VGPRs) pinned in registers via asm barrier (stop remat)
//  - s1 rows double-buffered as raw float4, load issued one iteration before
//    the FMAs that consume it (hide L1/L2 latency under the previous scan)
//  - next-row cost FMAs placed before the scan so they fill DPP stall slots

#define TL1 512
#define TL2 512
#define TD  16
#define TNB 128
#define BIGF 3.0e38f

typedef float f32x2 __attribute__((ext_vector_type(2)));
typedef float f32x4 __attribute__((ext_vector_type(4)));

__device__ inline f32x2 pk_fma(f32x2 a, f32x2 b, f32x2 c) {
    f32x2 d;
    asm("v_pk_fma_f32 %0, %1, %2, %3" : "=v"(d) : "v"(a), "v"(b), "v"(c));
    return d;
}

template<int CTRL, int RM>
__device__ inline float dppf(float old_, float src) {
    return __int_as_float(__builtin_amdgcn_update_dpp(
        __float_as_int(old_), __float_as_int(src), CTRL, RM, 0xf, false));
}

#define SSTEP(CTRL, RM) { \
    float Ct = dppf<CTRL, RM>(0.0f, C); \
    float At = dppf<CTRL, RM>(BIGF, A); \
    A = fminf(At + C, A); \
    C = Ct + C; \
}

#define ROW_SCAN() { \
    float C = cc[0], A = a[0]; \
    Cl[0] = C; Al[0] = A; \
    _Pragma("unroll") \
    for (int k = 1; k < 8; ++k) { \
        A = fminf(A + cc[k], a[k]); \
        C = C + cc[k]; \
        Cl[k] = C; Al[k] = A; \
    } \
    SSTEP(0x111, 0xf)  /* row_shr:1  */ \
    SSTEP(0x112, 0xf)  /* row_shr:2  */ \
    SSTEP(0x114, 0xf)  /* row_shr:4  */ \
    SSTEP(0x118, 0xf)  /* row_shr:8  */ \
    SSTEP(0x142, 0xa)  /* bcast15 -> rows 1,3 */ \
    SSTEP(0x143, 0xc)  /* bcast31 -> rows 2,3 */ \
    float Apre = dppf<0x138, 0xf>(BIGF, A);  /* exclusive: wave_shr:1 */ \
    _Pragma("unroll") \
    for (int k = 0; k < 8; ++k) prev[k] = fminf(Apre + Cl[k], Al[k]); \
}

__device__ inline void load_raw(const float* __restrict__ s1b, int i, f32x4* dst) {
    const f32x4* p = reinterpret_cast<const f32x4*>(s1b + i * TD);
    #pragma unroll
    for (int q = 0; q < 4; ++q) dst[q] = p[q];
}

__device__ inline void fma_costs(const f32x4* xv, const f32x2 (&y2)[8][8],
                                 const float* ysq, float* c) {
    f32x2 x2[8];
    #pragma unroll
    for (int q = 0; q < 4; ++q) {
        x2[2 * q]     = f32x2{xv[q].x, xv[q].y};
        x2[2 * q + 1] = f32x2{xv[q].z, xv[q].w};
    }
    f32x2 xs = {0.f, 0.f};
    #pragma unroll
    for (int p = 0; p < 8; ++p) xs = pk_fma(x2[p], x2[p], xs);
    float xsq = xs.x + xs.y;
    #pragma unroll
    for (int k = 0; k < 8; ++k) {
        f32x2 acc = {0.f, 0.f};
        #pragma unroll
        for (int p = 0; p < 8; ++p) acc = pk_fma(x2[p], y2[k][p], acc);
        c[k] = fmaf(-2.f, acc.x + acc.y, xsq + ysq[k]);
    }
}

__global__ __launch_bounds__(64, 1) void dtw_dp_kernel(const float* __restrict__ s1,
                                                       const float* __restrict__ s2,
                                                       float* __restrict__ ws) {
    const int b = blockIdx.x;
    const int t = threadIdx.x;   // lane 0..63

    // y: 8 columns x 16 dims in registers; ysq per column
    const float* s2b = s2 + ((size_t)b * TL2 + 8 * (size_t)t) * TD;
    f32x2 y2[8][8];
    float ysq[8];
    #pragma unroll
    for (int k = 0; k < 8; ++k) {
        #pragma unroll
        for (int p = 0; p < 8; ++p)
            y2[k][p] = *reinterpret_cast<const f32x2*>(s2b + k * TD + 2 * p);
        f32x2 acc = {0.f, 0.f};
        #pragma unroll
        for (int p = 0; p < 8; ++p) acc = pk_fma(y2[k][p], y2[k][p], acc);
        ysq[k] = acc.x + acc.y;
    }
    // pin y2 in VGPRs: make values opaque so the compiler cannot re-load them
    #pragma unroll
    for (int k = 0; k < 8; ++k) {
        #pragma unroll
        for (int p = 0; p < 8; ++p)
            asm volatile("" : "+v"(y2[k][p]));
    }

    const float* s1b = s1 + (size_t)b * TL1 * TD;

    f32x4 bufA[4], bufB[4];          // raw s1 rows: row r lives in (r&1)?B:A
    load_raw(s1b, 0, bufA);
    load_raw(s1b, 1, bufB);

    float cc[8], cn[8];
    fma_costs(bufA, y2, ysq, cc);    // costs row 0

    float prev[8], Cl[8], Al[8];

    {   // row 0 (peeled): only entry is (0,0)
        load_raw(s1b, 2, bufA);      // prefetch raw row 2
        float a[8];
        #pragma unroll
        for (int k = 0; k < 8; ++k)
            a[k] = cc[k] + ((t == 0 && k == 0) ? 0.f : BIGF);
        ROW_SCAN();
        fma_costs(bufB, y2, ysq, cc);  // costs row 1 (load was 1 scan ago)
    }

    #pragma unroll 2
    for (int i = 1; i < TL1; ++i) {
        if (i + 2 < TL1) load_raw(s1b, i + 2, (i & 1) ? bufB : bufA);
        if (i + 1 < TL1) fma_costs((i & 1) ? bufA : bufB, y2, ysq, cn); // row i+1

        float a[8];
        float pe = dppf<0x138, 0xf>(BIGF, prev[7]);   // DTW(i-1, 8t-1)
        float m0 = (t == 0) ? prev[0] : fminf(prev[0], pe);
        a[0] = cc[0] + m0;
        #pragma unroll
        for (int k = 1; k < 8; ++k)
            a[k] = cc[k] + fminf(prev[k], prev[k - 1]);

        ROW_SCAN();

        #pragma unroll
        for (int k = 0; k < 8; ++k) cc[k] = cn[k];
    }

    if (t == 63) ws[b] = sqrtf(prev[7]);
}

__global__ void dtw_reduce_kernel(const float* __restrict__ ws, float* __restrict__ out) {
    const int t = threadIdx.x;          // 64 threads
    float v = ws[t] + ws[t + 64];
    #pragma unroll
    for (int d2 = 32; d2 > 0; d2 >>= 1) v += __shfl_down(v, d2);
    if (t == 0) out[0] = v * (1.0f / TNB);
}

extern "C" void kernel_launch(void* const* d_in, const int* in_sizes, int n_in,
                              void* d_out, int out_size, void* d_ws, size_t ws_size,
                              hipStream_t stream) {
    const float* s1 = (const float*)d_in[0];
    const float* s2 = (const float*)d_in[1];
    float* ws  = (float*)d_ws;
    float* out = (float*)d_out;

    dtw_dp_kernel<<<TNB, 64, 0, stream>>>(s1, s2, ws);
    dtw_reduce_kernel<<<1, 64, 0, stream>>>(ws, out);
}

// Round 5
// 148.116 us; speedup vs baseline: 2.8222x; 1.3476x over previous
//
#include <hip/hip_runtime.h>
#include <math.h>

// DTW loss: B=128, L1=L2=512, D=16.
// R5: producer/consumer block. 5 waves per batch-block:
//   wave 0  = consumer: DPP (min,+) pair-scan over rows, costs read from LDS
//   waves 1-4 = producers: each owns 128 columns, computes ||x_i - y_j||^2
//     for 8-row chunks into a double-buffered LDS cost buffer.
// One __syncthreads per 8-row chunk. The serial scan wave carries no
// cost-FMA / tile-residency burden -> its ~200cy/row issue is the floor.

#define TL1 512
#define TL2 512
#define TD  16
#define TNB 128
#define BIGF 3.0e38f
#define CHUNK 8
#define NCHUNK (TL1 / CHUNK)   // 64

typedef float f32x2 __attribute__((ext_vector_type(2)));
typedef float f32x4 __attribute__((ext_vector_type(4)));

__device__ inline f32x2 pk_fma(f32x2 a, f32x2 b, f32x2 c) {
    f32x2 d;
    asm("v_pk_fma_f32 %0, %1, %2, %3" : "=v"(d) : "v"(a), "v"(b), "v"(c));
    return d;
}

template<int CTRL, int RM>
__device__ inline float dppf(float old_, float src) {
    return __int_as_float(__builtin_amdgcn_update_dpp(
        __float_as_int(old_), __float_as_int(src), CTRL, RM, 0xf, false));
}

#define SSTEP(CTRL, RM) { \
    float Ct = dppf<CTRL, RM>(0.0f, C); \
    float At = dppf<CTRL, RM>(BIGF, A); \
    A = fminf(At + C, A); \
    C = Ct + C; \
}

#define ROW_SCAN() { \
    float C = cc[0], A = a[0]; \
    Cl[0] = C; Al[0] = A; \
    _Pragma("unroll") \
    for (int k = 1; k < 8; ++k) { \
        A = fminf(A + cc[k], a[k]); \
        C = C + cc[k]; \
        Cl[k] = C; Al[k] = A; \
    } \
    SSTEP(0x111, 0xf)  /* row_shr:1  */ \
    SSTEP(0x112, 0xf)  /* row_shr:2  */ \
    SSTEP(0x114, 0xf)  /* row_shr:4  */ \
    SSTEP(0x118, 0xf)  /* row_shr:8  */ \
    SSTEP(0x142, 0xa)  /* bcast15 -> rows 1,3 */ \
    SSTEP(0x143, 0xc)  /* bcast31 -> rows 2,3 */ \
    float Apre = dppf<0x138, 0xf>(BIGF, A);  /* exclusive: wave_shr:1 */ \
    _Pragma("unroll") \
    for (int k = 0; k < 8; ++k) prev[k] = fminf(Apre + Cl[k], Al[k]); \
}

__device__ inline void load_raw(const float* __restrict__ s1b, int i, f32x4* dst) {
    const f32x4* p = reinterpret_cast<const f32x4*>(s1b + i * TD);
    #pragma unroll
    for (int q = 0; q < 4; ++q) dst[q] = p[q];
}

__global__ __launch_bounds__(320, 1) void dtw_fused_kernel(const float* __restrict__ s1,
                                                           const float* __restrict__ s2,
                                                           float* __restrict__ ws) {
    const int b   = blockIdx.x;
    const int tid = threadIdx.x;
    const int w   = tid >> 6;    // wave 0..4
    const int t   = tid & 63;    // lane

    __shared__ float cost[2][CHUNK][TL2];   // 32 KB, double-buffered chunks

    const float* s1b = s1 + (size_t)b * TL1 * TD;

    // ---- consumer state (wave 0) ----
    float prev[8], Cl[8], Al[8];

    // ---- producer state (waves 1..4): 2 columns/lane ----
    const int c0 = (w - 1) * 128 + 2 * t;   // valid for w>=1
    f32x2 y2p[2][8];
    float ysq[2];
    f32x4 xb0[4], xb1[4], xb2[4], xb3[4];   // x-row ring, depth 4 (static idx)

    if (w > 0) {
        #pragma unroll
        for (int cq = 0; cq < 2; ++cq) {
            const float* yp = s2 + ((size_t)b * TL2 + (c0 + cq)) * TD;
            #pragma unroll
            for (int p = 0; p < 8; ++p)
                y2p[cq][p] = *reinterpret_cast<const f32x2*>(yp + 2 * p);
            f32x2 acc = {0.f, 0.f};
            #pragma unroll
            for (int p = 0; p < 8; ++p) acc = pk_fma(y2p[cq][p], y2p[cq][p], acc);
            ysq[cq] = acc.x + acc.y;
        }
        load_raw(s1b, 0, xb0);
        load_raw(s1b, 1, xb1);
        load_raw(s1b, 2, xb2);
        load_raw(s1b, 3, xb3);
    }

    for (int chunk = 0; chunk < NCHUNK + 1; ++chunk) {
        if (w > 0) {
            if (chunk < NCHUNK) {
                // produce rows chunk*8 .. chunk*8+7 into cost[chunk&1]
                #pragma unroll
                for (int r = 0; r < 8; ++r) {
                    const int i = chunk * CHUNK + r;
                    f32x4* xb = ((r & 3) == 0) ? xb0 : ((r & 3) == 1) ? xb1
                              : ((r & 3) == 2) ? xb2 : xb3;
                    f32x2 x2[8];
                    #pragma unroll
                    for (int q = 0; q < 4; ++q) {
                        x2[2 * q]     = f32x2{xb[q].x, xb[q].y};
                        x2[2 * q + 1] = f32x2{xb[q].z, xb[q].w};
                    }
                    f32x2 xs = {0.f, 0.f};
                    #pragma unroll
                    for (int p = 0; p < 8; ++p) xs = pk_fma(x2[p], x2[p], xs);
                    const float xsq = xs.x + xs.y;
                    float cv[2];
                    #pragma unroll
                    for (int cq = 0; cq < 2; ++cq) {
                        f32x2 acc = {0.f, 0.f};
                        #pragma unroll
                        for (int p = 0; p < 8; ++p) acc = pk_fma(x2[p], y2p[cq][p], acc);
                        cv[cq] = fmaf(-2.f, acc.x + acc.y, xsq + ysq[cq]);
                    }
                    *reinterpret_cast<f32x2*>(&cost[chunk & 1][r][c0]) = f32x2{cv[0], cv[1]};
                    if (i + 4 < TL1) load_raw(s1b, i + 4, xb);   // refill ring slot
                }
            }
        } else {
            if (chunk >= 1) {
                const int cb = (chunk - 1) & 1;
                // issue all 16 LDS reads for the chunk up-front
                f32x4 crow[8][2];
                #pragma unroll
                for (int r = 0; r < 8; ++r) {
                    crow[r][0] = *reinterpret_cast<const f32x4*>(&cost[cb][r][8 * t]);
                    crow[r][1] = *reinterpret_cast<const f32x4*>(&cost[cb][r][8 * t + 4]);
                }
                #pragma unroll
                for (int r = 0; r < 8; ++r) {
                    const int i = (chunk - 1) * CHUNK + r;
                    float cc[8] = {crow[r][0].x, crow[r][0].y, crow[r][0].z, crow[r][0].w,
                                   crow[r][1].x, crow[r][1].y, crow[r][1].z, crow[r][1].w};
                    float a[8];
                    if (i == 0) {
                        #pragma unroll
                        for (int k = 0; k < 8; ++k)
                            a[k] = cc[k] + ((t == 0 && k == 0) ? 0.f : BIGF);
                    } else {
                        float pe = dppf<0x138, 0xf>(BIGF, prev[7]);   // DTW(i-1, 8t-1)
                        float m0 = (t == 0) ? prev[0] : fminf(prev[0], pe);
                        a[0] = cc[0] + m0;
                        #pragma unroll
                        for (int k = 1; k < 8; ++k)
                            a[k] = cc[k] + fminf(prev[k], prev[k - 1]);
                    }
                    ROW_SCAN();
                }
            }
        }
        __syncthreads();
    }

    if (w == 0 && t == 63) ws[b] = sqrtf(prev[7]);
}

__global__ void dtw_reduce_kernel(const float* __restrict__ ws, float* __restrict__ out) {
    const int t = threadIdx.x;          // 64 threads
    float v = ws[t] + ws[t + 64];
    #pragma unroll
    for (int d2 = 32; d2 > 0; d2 >>= 1) v += __shfl_down(v, d2);
    if (t == 0) out[0] = v * (1.0f / TNB);
}

extern "C" void kernel_launch(void* const* d_in, const int* in_sizes, int n_in,
                              void* d_out, int out_size, void* d_ws, size_t ws_size,
                              hipStream_t stream) {
    const float* s1 = (const float*)d_in[0];
    const float* s2 = (const float*)d_in[1];
    float* ws  = (float*)d_ws;
    float* out = (float*)d_out;

    dtw_fused_kernel<<<TNB, 320, 0, stream>>>(s1, s2, ws);
    dtw_reduce_kernel<<<1, 64, 0, stream>>>(ws, out);
}

// Round 6
// 131.576 us; speedup vs baseline: 3.1769x; 1.1257x over previous
//
#include <hip/hip_runtime.h>
#include <math.h>

// DTW loss: B=128, L1=L2=512, D=16.
// R6: 3 waves/block: wave0 = consumer (DPP pair-scan), waves 1-2 = producers
// (4 cols/lane, ds_write_b128). Consumer chain shortened:
//  - tree-reduction (3 levels) to wave-scan totals; interior prefixes off-chain
//  - C-moves via bound_ctrl=1 single-instr DPP
//  - Apre reused as the diagonal boundary value (no extra wave_shr)

#define TL1 512
#define TL2 512
#define TD  16
#define TNB 128
#define BIGF 3.0e38f
#define CHUNK 8
#define NCHUNK (TL1 / CHUNK)   // 64

typedef float f32x2 __attribute__((ext_vector_type(2)));
typedef float f32x4 __attribute__((ext_vector_type(4)));

__device__ inline f32x2 pk_fma(f32x2 a, f32x2 b, f32x2 c) {
    f32x2 d;
    asm("v_pk_fma_f32 %0, %1, %2, %3" : "=v"(d) : "v"(a), "v"(b), "v"(c));
    return d;
}

template<int CTRL, int RM, bool BC>
__device__ inline float dpp_mov(float old_, float src) {
    return __int_as_float(__builtin_amdgcn_update_dpp(
        __float_as_int(old_), __float_as_int(src), CTRL, RM, 0xf, BC));
}

// wave pair-scan step on (C, A); C-identity 0 via bound_ctrl, A-identity BIG via old
#define WSTEP(CTRL, RM) { \
    float Ct = dpp_mov<CTRL, RM, true >(0.0f, C); \
    float At = dpp_mov<CTRL, RM, false>(BIGF, A); \
    A = fminf(At + C, A); \
    C = Ct + C; \
}

__device__ inline void load_raw(const float* __restrict__ s1b, int i, f32x4* dst) {
    const f32x4* p = reinterpret_cast<const f32x4*>(s1b + i * TD);
    #pragma unroll
    for (int q = 0; q < 4; ++q) dst[q] = p[q];
}

__global__ __launch_bounds__(192, 1) void dtw_fused_kernel(const float* __restrict__ s1,
                                                           const float* __restrict__ s2,
                                                           float* __restrict__ ws) {
    const int b   = blockIdx.x;
    const int tid = threadIdx.x;
    const int w   = tid >> 6;    // wave 0..2
    const int t   = tid & 63;    // lane

    __shared__ float cost[2][CHUNK][TL2];   // 32 KB double-buffered cost chunks

    const float* s1b = s1 + (size_t)b * TL1 * TD;

    // ---- consumer state ----
    float m[8];        // min(prev[k], prev[k-1]) carried between rows
    float lastP7 = 0.f;

    // ---- producer state (waves 1,2): 4 contiguous cols/lane ----
    const int c0 = (w - 1) * 256 + 4 * t;
    f32x2 y2p[4][8];
    float ysq[4];
    f32x4 xb0[4], xb1[4], xb2[4], xb3[4];

    if (w > 0) {
        #pragma unroll
        for (int cq = 0; cq < 4; ++cq) {
            const float* yp = s2 + ((size_t)b * TL2 + (c0 + cq)) * TD;
            #pragma unroll
            for (int p = 0; p < 8; ++p)
                y2p[cq][p] = *reinterpret_cast<const f32x2*>(yp + 2 * p);
            f32x2 acc = {0.f, 0.f};
            #pragma unroll
            for (int p = 0; p < 8; ++p) acc = pk_fma(y2p[cq][p], y2p[cq][p], acc);
            ysq[cq] = acc.x + acc.y;
        }
        load_raw(s1b, 0, xb0);
        load_raw(s1b, 1, xb1);
        load_raw(s1b, 2, xb2);
        load_raw(s1b, 3, xb3);
    }

    for (int chunk = 0; chunk < NCHUNK + 1; ++chunk) {
        if (w > 0) {
            if (chunk < NCHUNK) {
                #pragma unroll
                for (int r = 0; r < 8; ++r) {
                    const int i = chunk * CHUNK + r;
                    f32x4* xb = ((r & 3) == 0) ? xb0 : ((r & 3) == 1) ? xb1
                              : ((r & 3) == 2) ? xb2 : xb3;
                    f32x2 x2[8];
                    #pragma unroll
                    for (int q = 0; q < 4; ++q) {
                        x2[2 * q]     = f32x2{xb[q].x, xb[q].y};
                        x2[2 * q + 1] = f32x2{xb[q].z, xb[q].w};
                    }
                    f32x2 xs = {0.f, 0.f};
                    #pragma unroll
                    for (int p = 0; p < 8; ++p) xs = pk_fma(x2[p], x2[p], xs);
                    const float xsq = xs.x + xs.y;
                    f32x4 cv;
                    #pragma unroll
                    for (int cq = 0; cq < 4; ++cq) {
                        f32x2 acc = {0.f, 0.f};
                        #pragma unroll
                        for (int p = 0; p < 8; ++p) acc = pk_fma(x2[p], y2p[cq][p], acc);
                        cv[cq] = fmaf(-2.f, acc.x + acc.y, xsq + ysq[cq]);
                    }
                    *reinterpret_cast<f32x4*>(&cost[chunk & 1][r][c0]) = cv;
                    if (i + 4 < TL1) load_raw(s1b, i + 4, xb);
                }
            }
        } else {
            if (chunk >= 1) {
                const int cb = (chunk - 1) & 1;
                f32x4 crow[8][2];
                #pragma unroll
                for (int r = 0; r < 8; ++r) {
                    crow[r][0] = *reinterpret_cast<const f32x4*>(&cost[cb][r][8 * t]);
                    crow[r][1] = *reinterpret_cast<const f32x4*>(&cost[cb][r][8 * t + 4]);
                }
                #pragma unroll
                for (int r = 0; r < 8; ++r) {
                    const float cc[8] = {crow[r][0].x, crow[r][0].y, crow[r][0].z, crow[r][0].w,
                                         crow[r][1].x, crow[r][1].y, crow[r][1].z, crow[r][1].w};
                    float a[8];
                    if (chunk == 1 && r == 0) {
                        #pragma unroll
                        for (int k = 0; k < 8; ++k)
                            a[k] = cc[k] + ((t == 0 && k == 0) ? 0.f : BIGF);
                    } else {
                        #pragma unroll
                        for (int k = 0; k < 8; ++k)
                            a[k] = cc[k] + m[k];
                    }

                    // tree-reduce to wave-scan totals (3 combine levels)
                    float C01 = cc[0] + cc[1], A01 = fminf(a[0] + cc[1], a[1]);
                    float C23 = cc[2] + cc[3], A23 = fminf(a[2] + cc[3], a[3]);
                    float C45 = cc[4] + cc[5], A45 = fminf(a[4] + cc[5], a[5]);
                    float C67 = cc[6] + cc[7], A67 = fminf(a[6] + cc[7], a[7]);
                    float C03 = C01 + C23,     A03 = fminf(A01 + C23, A23);
                    float C47 = C45 + C67,     A47 = fminf(A45 + C67, A67);
                    float C   = C03 + C47;
                    float A   = fminf(A03 + C47, A47);

                    // 6-step wave scan (DPP)
                    WSTEP(0x111, 0xf)   // row_shr:1
                    WSTEP(0x112, 0xf)   // row_shr:2
                    WSTEP(0x114, 0xf)   // row_shr:4
                    WSTEP(0x118, 0xf)   // row_shr:8
                    WSTEP(0x142, 0xa)   // row_bcast:15 -> rows 1,3
                    WSTEP(0x143, 0xc)   // row_bcast:31 -> rows 2,3

                    // interior prefixes (off the DPP chain; scheduler interleaves)
                    float Cl[8], Al[8];
                    Cl[0] = cc[0]; Al[0] = a[0];
                    #pragma unroll
                    for (int k = 1; k < 8; ++k) {
                        Al[k] = fminf(Al[k - 1] + cc[k], a[k]);
                        Cl[k] = Cl[k - 1] + cc[k];
                    }

                    // exclusive prefix; also == prev[7] of lane t-1 (diag boundary)
                    float Apre = dpp_mov<0x138, 0xf, false>(BIGF, A);

                    float pv[8];
                    #pragma unroll
                    for (int k = 0; k < 8; ++k)
                        pv[k] = fminf(Apre + Cl[k], Al[k]);

                    m[0] = fminf(pv[0], Apre);   // lane0: Apre=BIG -> pv[0]
                    #pragma unroll
                    for (int k = 1; k < 8; ++k)
                        m[k] = fminf(pv[k], pv[k - 1]);

                    lastP7 = pv[7];
                }
            }
        }
        __syncthreads();
    }

    if (w == 0 && t == 63) ws[b] = sqrtf(lastP7);
}

__global__ void dtw_reduce_kernel(const float* __restrict__ ws, float* __restrict__ out) {
    const int t = threadIdx.x;          // 64 threads
    float v = ws[t] + ws[t + 64];
    #pragma unroll
    for (int d2 = 32; d2 > 0; d2 >>= 1) v += __shfl_down(v, d2);
    if (t == 0) out[0] = v * (1.0f / TNB);
}

extern "C" void kernel_launch(void* const* d_in, const int* in_sizes, int n_in,
                              void* d_out, int out_size, void* d_ws, size_t ws_size,
                              hipStream_t stream) {
    const float* s1 = (const float*)d_in[0];
    const float* s2 = (const float*)d_in[1];
    float* ws  = (float*)d_ws;
    float* out = (float*)d_out;

    dtw_fused_kernel<<<TNB, 192, 0, stream>>>(s1, s2, ws);
    dtw_reduce_kernel<<<1, 64, 0, stream>>>(ws, out);
}